// Round 2
// baseline (230.729 us; speedup 1.0000x reference)
//
#include <hip/hip_runtime.h>

// Morton decode: out[b,c,i,j] = x[b,c,ij], i = odd bits of ij, j = even bits.
// B=8, C=64, L=65536 (S=256), fp32.
//
// R3: kill the 1KB-strided write scatter (DRAM page thrash) with an LDS
// transpose. One block = one half-band of output (32 rows x 256 cols =
// 32 KB FULLY CONTIGUOUS write range). Sources: rows 0..31 of a tile are
// exactly the first 8 KB of its Morton range, so the half-band reads four
// contiguous 8 KB chunks (tiles tj=0..3) -- per-instruction read
// coalescing identical to R1/R2. Patches bounce through a 32x260 LDS tile
// (stride 260 == 4 mod 32 banks -> both phases exactly minimal bank
// cycles, verified 8 lanes per 16B slot uniform), then each wave stores
// full 1 KB contiguous output rows: the write stream is page-sequential
// like a copy/fill.

typedef float f32x4 __attribute__((ext_vector_type(4)));

__device__ __forceinline__ unsigned compact1by1(unsigned x) {
    // compact the even-position bits of x into the low bits
    x &= 0x55555555u;
    x = (x ^ (x >> 1)) & 0x33333333u;
    x = (x ^ (x >> 2)) & 0x0f0f0f0fu;
    x = (x ^ (x >> 4)) & 0x00ff00ffu;
    return x;
}

#define LDSW 260u  // 256 + 4 pad floats: row stride = 4 banks mod 32

__global__ __launch_bounds__(256) void Morton_decode_69312182223578_kernel(
        const float* __restrict__ x, float* __restrict__ out) {
    __shared__ float lds[32u * LDSW];

    const unsigned b     = blockIdx.x;
    const unsigned bc    = b >> 3;      // image index 0..511 (B*C)
    const unsigned rem   = b & 7u;      // half-band index within image
    const unsigned ti    = rem >> 1;    // tile row 0..3
    const unsigned ihalf = rem & 1u;    // which 32-row half of the tile row

    const unsigned t = threadIdx.x;
    const float* img = x + (size_t)bc * 65536u;

    // Load: 4 tiles (tj=0..3), first/second 8 KB of each (rows 0..31 of the
    // tile == Morton groups with i5==ihalf). 8 independent 16 B loads.
    f32x4 v[4][2];
#pragma unroll
    for (unsigned c = 0; c < 4; ++c) {
        const unsigned tm = (c & 1u) | ((ti & 1u) << 1)
                          | ((c >> 1) << 2) | ((ti >> 1) << 3);
        const f32x4* src = (const f32x4*)(img + ((size_t)tm << 12) + (ihalf << 11));
        v[c][0] = src[2u * t + 0u];
        v[c][1] = src[2u * t + 1u];
    }

    // Thread t covers quads m={2b,2b+1} of Morton group g=t>>1 (per chunk).
    // g bits (0..6) = j2,i2,j3,i3,j4,i4,j5.
    const unsigned g   = t >> 1;
    const unsigned bq  = t & 1u;               // i1
    const unsigned Jh  = compact1by1(g);       // j2..j5  (0..15)
    const unsigned Ihp = compact1by1(g >> 1);  // i2..i4  (0..7)
    const unsigned r   = 4u * Ihp + 2u * bq;   // local row 0..30

#pragma unroll
    for (unsigned c = 0; c < 4; ++c) {
        const unsigned col = c * 64u + 4u * Jh;
        // quad m=2b:(r,col) m=2b+1:(r,col+2); .x=(r,c) .y=(r,c+1) .z/.w=row+1
        f32x4 w0 = {v[c][0].x, v[c][0].y, v[c][1].x, v[c][1].y};
        f32x4 w1 = {v[c][0].z, v[c][0].w, v[c][1].z, v[c][1].w};
        *(f32x4*)(&lds[r * LDSW + col])        = w0;
        *(f32x4*)(&lds[(r + 1u) * LDSW + col]) = w1;
    }

    __syncthreads();

    // Store: 8 x (one full 1 KB output row per wave), 32 KB contiguous
    // per block -> page-sequential write stream.
    float* obase = out + (size_t)bc * 65536u + (size_t)(2u * ti + ihalf) * 8192u;
    const unsigned w_id  = t >> 6;          // wave 0..3
    const unsigned lane4 = (t & 63u) * 4u;  // float offset within row
#pragma unroll
    for (unsigned s = 0; s < 8; ++s) {
        const unsigned rr = s * 4u + w_id;  // local row 0..31
        f32x4 w = *(const f32x4*)(&lds[rr * LDSW + lane4]);
        __builtin_nontemporal_store(w, (f32x4*)(obase + rr * 256u + lane4));
    }
}

extern "C" void kernel_launch(void* const* d_in, const int* in_sizes, int n_in,
                              void* d_out, int out_size, void* d_ws, size_t ws_size,
                              hipStream_t stream) {
    const float* x = (const float*)d_in[0];
    float* out = (float*)d_out;
    // 512 images * 8 half-bands = 4096 blocks, one pass per block
    Morton_decode_69312182223578_kernel<<<4096, 256, 0, stream>>>(x, out);
}

// Round 3
// 229.630 us; speedup vs baseline: 1.0048x; 1.0048x over previous
//
#include <hip/hip_runtime.h>

// Morton decode: out[b,c,i,j] = x[b,c,ij], i = odd bits of ij, j = even bits.
// B=8, C=64, L=65536 (S=256), fp32.
//
// R4: ablation — identical to R3 except NONTEMPORAL STORES REMOVED.
// R1 (strided scatter, occ 59%), R2 (2x MLP), R3 (LDS transpose,
// page-sequential 32 KB write bursts) all measured ~80-85 us @ ~2.4 TB/s:
// bottleneck is invariant to pattern/occupancy/MLP. The one thing all
// three share vs the 6.7 TB/s fill is the nt store policy (L2 bypass ->
// no write aggregation). This round isolates it.
//
// Structure (unchanged from R3): one block = one half-band of output
// (32 rows x 256 cols = 32 KB contiguous). Reads four contiguous 8 KB
// chunks (one per tile column). 32x260-padded LDS transpose, then each
// wave stores full 1 KB contiguous output rows.

typedef float f32x4 __attribute__((ext_vector_type(4)));

__device__ __forceinline__ unsigned compact1by1(unsigned x) {
    // compact the even-position bits of x into the low bits
    x &= 0x55555555u;
    x = (x ^ (x >> 1)) & 0x33333333u;
    x = (x ^ (x >> 2)) & 0x0f0f0f0fu;
    x = (x ^ (x >> 4)) & 0x00ff00ffu;
    return x;
}

#define LDSW 260u  // 256 + 4 pad floats: row stride = 4 banks mod 32

__global__ __launch_bounds__(256) void Morton_decode_69312182223578_kernel(
        const float* __restrict__ x, float* __restrict__ out) {
    __shared__ float lds[32u * LDSW];

    const unsigned b     = blockIdx.x;
    const unsigned bc    = b >> 3;      // image index 0..511 (B*C)
    const unsigned rem   = b & 7u;      // half-band index within image
    const unsigned ti    = rem >> 1;    // tile row 0..3
    const unsigned ihalf = rem & 1u;    // which 32-row half of the tile row

    const unsigned t = threadIdx.x;
    const float* img = x + (size_t)bc * 65536u;

    // Load: 4 tiles (tj=0..3), first/second 8 KB of each (rows 0..31 of the
    // tile == Morton groups with i5==ihalf). 8 independent 16 B loads.
    f32x4 v[4][2];
#pragma unroll
    for (unsigned c = 0; c < 4; ++c) {
        const unsigned tm = (c & 1u) | ((ti & 1u) << 1)
                          | ((c >> 1) << 2) | ((ti >> 1) << 3);
        const f32x4* src = (const f32x4*)(img + ((size_t)tm << 12) + (ihalf << 11));
        v[c][0] = src[2u * t + 0u];
        v[c][1] = src[2u * t + 1u];
    }

    // Thread t covers quads m={2b,2b+1} of Morton group g=t>>1 (per chunk).
    // g bits (0..6) = j2,i2,j3,i3,j4,i4,j5.
    const unsigned g   = t >> 1;
    const unsigned bq  = t & 1u;               // i1
    const unsigned Jh  = compact1by1(g);       // j2..j5  (0..15)
    const unsigned Ihp = compact1by1(g >> 1);  // i2..i4  (0..7)
    const unsigned r   = 4u * Ihp + 2u * bq;   // local row 0..30

#pragma unroll
    for (unsigned c = 0; c < 4; ++c) {
        const unsigned col = c * 64u + 4u * Jh;
        // quad m=2b:(r,col) m=2b+1:(r,col+2); .x=(r,c) .y=(r,c+1) .z/.w=row+1
        f32x4 w0 = {v[c][0].x, v[c][0].y, v[c][1].x, v[c][1].y};
        f32x4 w1 = {v[c][0].z, v[c][0].w, v[c][1].z, v[c][1].w};
        *(f32x4*)(&lds[r * LDSW + col])        = w0;
        *(f32x4*)(&lds[(r + 1u) * LDSW + col]) = w1;
    }

    __syncthreads();

    // Store: 8 x (one full 1 KB output row per wave), 32 KB contiguous
    // per block. PLAIN stores (the single variable changed this round).
    float* obase = out + (size_t)bc * 65536u + (size_t)(2u * ti + ihalf) * 8192u;
    const unsigned w_id  = t >> 6;          // wave 0..3
    const unsigned lane4 = (t & 63u) * 4u;  // float offset within row
#pragma unroll
    for (unsigned s = 0; s < 8; ++s) {
        const unsigned rr = s * 4u + w_id;  // local row 0..31
        f32x4 w = *(const f32x4*)(&lds[rr * LDSW + lane4]);
        *(f32x4*)(obase + rr * 256u + lane4) = w;
    }
}

extern "C" void kernel_launch(void* const* d_in, const int* in_sizes, int n_in,
                              void* d_out, int out_size, void* d_ws, size_t ws_size,
                              hipStream_t stream) {
    const float* x = (const float*)d_in[0];
    float* out = (float*)d_out;
    // 512 images * 8 half-bands = 4096 blocks, one pass per block
    Morton_decode_69312182223578_kernel<<<4096, 256, 0, stream>>>(x, out);
}

// Round 4
// 228.208 us; speedup vs baseline: 1.0110x; 1.0062x over previous
//
#include <hip/hip_runtime.h>

// Morton decode: out[b,c,i,j] = x[b,c,ij], i = odd bits of ij, j = even bits.
// B=8, C=64, L=65536 (S=256), fp32.
//
// R5: ablation — PER-INSTRUCTION-DENSE LOADS (copy-identical read stream).
// R1-R4 pinned 2.4-2.5 TB/s regardless of write pattern, MLP, occupancy,
// and NT policy. The one copy-property never tried: all prior variants
// load with 32-64 B lane stride (each 128 B segment half/quarter-requested
// per instruction -> 2-4x transactions per useful byte, outstanding-request
// slots carry half-empty payloads). Here thread t loads flat f32x4 {t,
// t+256} of each 8 KB chunk: lane stride 16 B, every global_load_dwordx4
// covers 8 fully-dense 128 B segments, exactly like the 6.3 TB/s copy.
// Morton unscramble moves into LDS-write addressing (2x ds_write_b64 per
// quad, ~2-way bank aliasing = free). Store phase unchanged from R4.
//
// Structure: one block = one half-band of output (32 rows x 256 cols =
// 32 KB contiguous). Reads four contiguous 8 KB chunks (tiles tj=0..3 of
// tile-row ti, half ihalf). 32x260-padded LDS; each wave stores full 1 KB
// contiguous output rows.

typedef float f32x4 __attribute__((ext_vector_type(4)));
typedef float f32x2 __attribute__((ext_vector_type(2)));

__device__ __forceinline__ unsigned compact1by1(unsigned x) {
    // compact the even-position bits of x into the low bits
    x &= 0x55555555u;
    x = (x ^ (x >> 1)) & 0x33333333u;
    x = (x ^ (x >> 2)) & 0x0f0f0f0fu;
    x = (x ^ (x >> 4)) & 0x00ff00ffu;
    return x;
}

#define LDSW 260u  // 256 + 4 pad floats

__global__ __launch_bounds__(256) void Morton_decode_69312182223578_kernel(
        const float* __restrict__ x, float* __restrict__ out) {
    __shared__ float lds[32u * LDSW];

    const unsigned b     = blockIdx.x;
    const unsigned bc    = b >> 3;      // image index 0..511 (B*C)
    const unsigned rem   = b & 7u;      // half-band index within image
    const unsigned ti    = rem >> 1;    // tile row 0..3
    const unsigned ihalf = rem & 1u;    // which 32-row half of the tile row

    const unsigned t = threadIdx.x;
    const float* img = x + (size_t)bc * 65536u;

    // Dense loads: 4 chunks x 2 f32x4, lane stride 16 B per instruction.
    f32x4 v[4][2];
#pragma unroll
    for (unsigned c = 0; c < 4; ++c) {
        const unsigned tm = (c & 1u) | ((ti & 1u) << 1)
                          | ((c >> 1) << 2) | ((ti >> 1) << 3);
        const f32x4* src = (const f32x4*)(img + ((size_t)tm << 12) + (ihalf << 11));
        v[c][0] = src[t];          // quads q = t       (j5=0)
        v[c][1] = src[t + 256u];   // quads q = t + 256 (j5=1)
    }

    // Quad q bits (0..8) = j1,i1,j2,i2,j3,i3,j4,i4,j5.
    // For q=t: I = i1..i4 = even bits of (t>>1); J = j1..j4 = even bits of t.
    const unsigned I = compact1by1(t >> 1);  // 0..15
    const unsigned J = compact1by1(t);       // 0..15
    const unsigned r = 2u * I;               // local row 0..30

    // Quad elements: .x=(r,col) .y=(r,col+1) .z=(r+1,col) .w=(r+1,col+1)
#pragma unroll
    for (unsigned c = 0; c < 4; ++c) {
#pragma unroll
        for (unsigned h = 0; h < 2; ++h) {
            const unsigned col = c * 64u + 32u * h + 2u * J;
            const f32x4 q = v[c][h];
            *(f32x2*)(&lds[r * LDSW + col])        = (f32x2){q.x, q.y};
            *(f32x2*)(&lds[(r + 1u) * LDSW + col]) = (f32x2){q.z, q.w};
        }
    }

    __syncthreads();

    // Store: 8 x (one full 1 KB output row per wave), 32 KB contiguous
    // per block; dense 16 B/lane per instruction.
    float* obase = out + (size_t)bc * 65536u + (size_t)(2u * ti + ihalf) * 8192u;
    const unsigned w_id  = t >> 6;          // wave 0..3
    const unsigned lane4 = (t & 63u) * 4u;  // float offset within row
#pragma unroll
    for (unsigned s = 0; s < 8; ++s) {
        const unsigned rr = s * 4u + w_id;  // local row 0..31
        f32x4 w = *(const f32x4*)(&lds[rr * LDSW + lane4]);
        *(f32x4*)(obase + rr * 256u + lane4) = w;
    }
}

extern "C" void kernel_launch(void* const* d_in, const int* in_sizes, int n_in,
                              void* d_out, int out_size, void* d_ws, size_t ws_size,
                              hipStream_t stream) {
    const float* x = (const float*)d_in[0];
    float* out = (float*)d_out;
    // 512 images * 8 half-bands = 4096 blocks, one pass per block
    Morton_decode_69312182223578_kernel<<<4096, 256, 0, stream>>>(x, out);
}